// Round 14
// baseline (240.963 us; speedup 1.0000x reference)
//
#include <hip/hip_runtime.h>
#include <stdint.h>

#define N_ROWS  8192   // B*S = 4*2048
#define DIM     256
#define K_CODES 8192
#define SPLITK  16
#define KS      512           // codes per split
#define LSLOTS  15            // per-row append slots in LDS (LDS = exactly 48 KiB)
#define GSLOTS  8             // per-row-split survivor slots in ws (top-8 by dot)
// acc-space (dot) margin: covers dist-bucket/2 (1.5e-5) + 2*bf16 dot err max
// (~4.5e-5) + dropped cnorm/2 (1.9e-6). 1e-4 leaves ~1.6x slack.
#define MARGIN_ACC 1.0e-4f
// finalize margin: MARGIN_ACC + 2x bf16 quantization of stored dots
// (|dot| <= ~0.04 -> qerr <= 6.3e-5 per side). 2.5e-4 covers 2.26e-4 worst.
#define MARGIN_FIN 2.5e-4f

typedef unsigned long long u64;
typedef unsigned short u16;
typedef short s16x8 __attribute__((ext_vector_type(8)));   // 8 bf16 = 4 VGPR
typedef float f32x4 __attribute__((ext_vector_type(4)));

__device__ __forceinline__ u64 u64min(u64 a, u64 b) { return a < b ? a : b; }

// float -> bf16 bits, round-to-nearest-even (no NaN inputs here)
__device__ __forceinline__ u16 f2bf(float f) {
    unsigned u = __float_as_uint(f);
    u += 0x7fffu + ((u >> 16) & 1u);
    return (u16)(u >> 16);
}

// async 16B global->LDS (dest = wave-uniform base + lane*16, HW-added)
__device__ __forceinline__ void gld16(void* lds, const void* g) {
    __builtin_amdgcn_global_load_lds(
        (const __attribute__((address_space(1))) unsigned int*)g,
        (__attribute__((address_space(3))) unsigned int*)lds, 16, 0, 0);
}

// ---------------------------------------------------------------- kernel A
// Fused: bf16 conversion of z_e & cb + row norms. One wave per row.
__global__ __launch_bounds__(256) void vq_prep(const float* __restrict__ z_e,
                                               const float* __restrict__ cb,
                                               u16* __restrict__ zb,
                                               u16* __restrict__ cbb,
                                               float* __restrict__ xnorm,
                                               float* __restrict__ cnorm) {
    int wid  = (blockIdx.x * 256 + threadIdx.x) >> 6;
    int lane = threadIdx.x & 63;
    const float* src; u16* d16; float* dn;
    if (wid < N_ROWS) { src = z_e + (size_t)wid * DIM; d16 = zb + (size_t)wid * DIM; dn = xnorm + wid; }
    else              { int k = wid - N_ROWS;
                        src = cb  + (size_t)k   * DIM; d16 = cbb + (size_t)k * DIM; dn = cnorm + k; }
    float4 v = *(const float4*)(src + lane * 4);
    ushort4 h;
    h.x = f2bf(v.x); h.y = f2bf(v.y); h.z = f2bf(v.z); h.w = f2bf(v.w);
    *(ushort4*)(d16 + lane * 4) = h;
    float s = (v.x * v.x + v.y * v.y) + (v.z * v.z + v.w * v.w);
#pragma unroll
    for (int off = 1; off < 64; off <<= 1)
        s += __shfl_xor(s, off, 64);
    if (lane == 0) *dn = s;
}

// ---------------------------------------------------------------- kernel B
// bf16 MFMA dot GEMM + per-row running MAX of dot (argmin dist == argmax dot)
// + margin-append. Block: 128 rows x 512 codes (one split), 4 waves, each a
// 32-row slab owning ALL codes of the split.
//
// R14: BARRIER-FREE wave-private staging rings (R8 design + its race fixed).
// Evidence: barrier-lockstep variants are pinned at 63-70us / ~20% occupancy
// across every resource configuration (R2,R5,R7,R9,R10,R13) -- the block-wide
// drain is structural. Each wave owns a private 2-slot x 4KB ring (32 codes
// x 64 dims per chunk, proven XOR-swizzle geometry) staged via gld16; ZERO
// block barriers in the K-loop.
//   R8's failure mode: a wave's QUEUED ds_reads of slot X (issued phase s-1;
//   compiler defers their lgkmcnt) can still be outstanding when the wave's
//   own next gld16 LDS-write to X lands -- gld16 writes (vmcnt domain) are
//   unordered vs queued ds_reads (lgkmcnt domain). FIX (intra-wave, no
//   barrier): s_waitcnt lgkmcnt(0) immediately BEFORE each STAGE.
// Phase s (64 phases: 16 tiles x 4 dim-chunks):
//   lgkmcnt(0) -> STAGE(s+1) -> vmcnt(4) -> 4x ds_read_b128(slot s&1) -> 8 MFMA
// FIFO invariant: outstanding at phase start = stage(s) exactly (af's 16
// loads are issued first and retire under phase 0's vmcnt(4)).
// Cost model: 4x intra-block staging redundancy = 1 GB from L2 (~30us floor)
// traded for zero lockstep; 4096 waves (16/CU supply, ~12 resident) hide it.
// LDS exactly 48 KiB: Cs 32768 + lcd 7680 + lci 7680 + lcnt 512 + gmaxs 512.
__global__ __launch_bounds__(256, 2) void vq_mfma(const u16* __restrict__ zb,
                                                  const u16* __restrict__ cbb,
                                                  int* __restrict__ cand_cnt,
                                                  unsigned* __restrict__ cand_pk) {
    __shared__ u16   Cs[4][2][32 * 64];   // 32 KB: per-wave 2-slot ring, swizzled
    __shared__ float lcd[128 * LSLOTS];   // 7.5 KB
    __shared__ int   lci[128 * LSLOTS];   // 7.5 KB
    __shared__ int   lcnt[128];
    __shared__ float gmaxs[128];

    const int tid   = threadIdx.x;
    const int lane  = tid & 63;
    const int wave  = tid >> 6;
    const int quad  = lane >> 4;
    const int l16   = lane & 15;
    const int split = blockIdx.x;
    const int n0    = blockIdx.y * 128;

    if (tid < 128) lcnt[tid] = 0;
    __syncthreads();   // lcnt init visible before any wave's first append;
                       // placed BEFORE any vmem issue so the vmcnt FIFO stays clean

    // staging lane constants: lane covers (row srow8 of 8-group, dest chunk schunk)
    const int srow8  = lane >> 3;
    const int schunk = lane & 7;
    const int ssw    = (schunk ^ srow8) * 8;   // swizzled source chunk offset (shorts)
    const u16* csrc  = cbb + (size_t)split * KS * DIM + (size_t)srow8 * DIM + ssw;

    // ---- A fragments in registers (issued FIRST: retire under phase 0's
    // vmcnt(4) by FIFO order). af[i][s]: row n0+wave*32+i*16+l16,
    // dims s*32 + quad*8 .. +7
    s16x8 af[2][8];
#pragma unroll
    for (int i = 0; i < 2; i++) {
        const u16* p = zb + (size_t)(n0 + wave * 32 + i * 16 + l16) * DIM + quad * 8;
#pragma unroll
        for (int s = 0; s < 8; s++)
            af[i][s] = *(const s16x8*)(p + s * 32);
    }

    u16* const ring0 = &Cs[wave][0][0];
    u16* const ring1 = &Cs[wave][1][0];

    // stage chunk s (ct = s>>2 : 32-code tile; kc = s&3 : 64-dim chunk) into
    // this wave's ring slot s&1. 4 gld16, each = 8 code-rows x 128B = 1KB.
    auto STAGE = [&](int s) {
        const int ct = s >> 2, kc = s & 3;
        u16* dst = (s & 1) ? ring1 : ring0;
        const u16* src = csrc + (size_t)(ct * 32) * DIM + kc * 64;
#pragma unroll
        for (int t = 0; t < 4; t++)
            gld16(dst + t * 512, src + (size_t)(t * 8) * DIM);
    };

    f32x4 acc[2][2];
    float runmax[8];
#pragma unroll
    for (int t = 0; t < 8; t++) runmax[t] = -3.0e38f;

    STAGE(0);   // prologue: af(16) + stage0(4) outstanding

    for (int ct = 0; ct < 16; ct++) {         // 16 tiles of 32 codes
        const int cb0 = split * KS + ct * 32;
#pragma unroll
        for (int i = 0; i < 2; i++)
#pragma unroll
            for (int j = 0; j < 2; j++)
#pragma unroll
                for (int e = 0; e < 4; e++) acc[i][j][e] = 0.0f;

#pragma unroll
        for (int kc = 0; kc < 4; kc++) {      // 64-dim chunks; s = ct*4+kc
            const int s = ct * 4 + kc;
            if (s < 63) {
                // drain own queued ds_reads (incl. phase s-1's reads of the
                // slot we are about to overwrite) -- THE R8 race fix.
                asm volatile("s_waitcnt lgkmcnt(0)" ::: "memory");
                STAGE(s + 1);                 // 1-ahead into the other slot
                // drain stage(s) (FIFO: leaves stage(s+1)'s 4 in flight)
                asm volatile("s_waitcnt vmcnt(4)" ::: "memory");
            } else {
                asm volatile("s_waitcnt vmcnt(0)" ::: "memory");
            }

            const u16* cbuf = (s & 1) ? ring1 : ring0;
#pragma unroll
            for (int ks = 0; ks < 2; ks++) {
                s16x8 bfr[2];
#pragma unroll
                for (int jj = 0; jj < 2; jj++)
                    bfr[jj] = *(const s16x8*)&cbuf[(jj * 16 + l16) * 64 +
                                                   (((ks << 2) | quad) ^ (l16 & 7)) * 8];
#pragma unroll
                for (int i = 0; i < 2; i++)
#pragma unroll
                    for (int jj = 0; jj < 2; jj++)
                        acc[i][jj] = __builtin_amdgcn_mfma_f32_16x16x32_bf16(
                            af[i][kc * 2 + ks], bfr[jj], acc[i][jj], 0, 0, 0);
            }
        }

        // ---- epilogue per 32-code tile: in-wave row max, runmax update,
        // margin appends. Row rl = wave*32+i*16+quad*4+r (wave-owned;
        // appends race only within the wave -> LDS atomics, no barrier).
#pragma unroll
        for (int i = 0; i < 2; i++)
#pragma unroll
            for (int r = 0; r < 4; r++) {
                float m = fmaxf(acc[i][0][r], acc[i][1][r]);
                m = fmaxf(m, __shfl_xor(m, 1, 64));
                m = fmaxf(m, __shfl_xor(m, 2, 64));
                m = fmaxf(m, __shfl_xor(m, 4, 64));
                m = fmaxf(m, __shfl_xor(m, 8, 64));
                runmax[i * 4 + r] = fmaxf(runmax[i * 4 + r], m);
                float thr = runmax[i * 4 + r] - MARGIN_ACC;
                int rl = wave * 32 + i * 16 + quad * 4 + r;
#pragma unroll
                for (int jj = 0; jj < 2; jj++) {
                    float d = acc[i][jj][r];
                    if (d >= thr) {
                        int pos = atomicAdd(&lcnt[rl], 1);
                        if (pos < LSLOTS) {
                            lcd[rl * LSLOTS + pos] = d;
                            lci[rl * LSLOTS + pos] = cb0 + jj * 16 + l16;
                        }
                    }
                }
            }
    }

    if (l16 == 0) {
#pragma unroll
        for (int i = 0; i < 2; i++)
#pragma unroll
            for (int r = 0; r < 4; r++)
                gmaxs[wave * 32 + i * 16 + quad * 4 + r] = runmax[i * 4 + r];
    }
    __syncthreads();

    // filter appends vs final row max; keep TOP-GSLOTS BY DOT (replace-min,
    // fp32 selection); store packed (bf16(dot)<<16)|idx so finalize can
    // margin-prefilter globally. [split][n] layout: contiguous private range.
    if (tid < 128) {
        int n   = n0 + tid;
        int cnt = lcnt[tid]; if (cnt > LSLOTS) cnt = LSLOTS;
        float thrf = gmaxs[tid] - MARGIN_ACC;
        float bd[GSLOTS]; int bi[GSLOTS];
        int w = 0;
        for (int s = 0; s < cnt; s++) {
            float d = lcd[tid * LSLOTS + s];
            if (d < thrf) continue;
            if (w < GSLOTS) { bd[w] = d; bi[w] = lci[tid * LSLOTS + s]; w++; }
            else {
                int mn = 0;
#pragma unroll
                for (int k = 1; k < GSLOTS; k++) if (bd[k] < bd[mn]) mn = k;
                if (d > bd[mn]) { bd[mn] = d; bi[mn] = lci[tid * LSLOTS + s]; }
            }
        }
        int base = (split * N_ROWS + n) * GSLOTS;
        for (int k = 0; k < w; k++)
            cand_pk[base + k] = ((unsigned)f2bf(bd[k]) << 16) | (unsigned)bi[k];
        cand_cnt[split * N_ROWS + n] = w;
    }
}

// ---------------------------------------------------------------- kernel C
// Gather packed candidates; global margin prefilter on bf16 dots
// (dot >= max_dot - MARGIN_FIN retains the true winner incl. quantization);
// exact fp32 recheck of the ~2-8 survivors with numerics BIT-IDENTICAL to
// the passing version (sequential fmaf d=0..255, fmaf(-2,m,xn)+cn,
// lexicographic (dist,idx) min); gather + z_q_st + rowloss. One wave/row.
__global__ __launch_bounds__(256) void vq_finalize(const float* __restrict__ z_e,
                                                   const float* __restrict__ cb,
                                                   const float* __restrict__ xnorm,
                                                   const float* __restrict__ cnorm,
                                                   const int* __restrict__ cand_cnt,
                                                   const unsigned* __restrict__ cand_pk,
                                                   float* __restrict__ out_zq,
                                                   float* __restrict__ out_idx,
                                                   float* __restrict__ rowloss) {
    const int n    = blockIdx.x * 4 + (threadIdx.x >> 6);
    const int lane = threadIdx.x & 63;

    int   myidx = -1;
    float mydot = -3.0e38f;
    int t = 0;
#pragma unroll
    for (int s = 0; s < SPLITK; s++) {
        int c = cand_cnt[s * N_ROWS + n];
        if (lane >= t && lane < t + c) {
            unsigned key = cand_pk[(s * N_ROWS + n) * GSLOTS + (lane - t)];
            myidx = (int)(key & 0x1FFFu);
            mydot = __uint_as_float(key & 0xFFFF0000u);
        }
        t += c;
    }

    // global (row-wide) max of stored bf16 dots
    float mg = mydot;
#pragma unroll
    for (int off = 1; off < 64; off <<= 1)
        mg = fmaxf(mg, __shfl_xor(mg, off, 64));

    u64 key = ~0ULL;
    if (myidx >= 0 && mydot >= mg - MARGIN_FIN) {   // ~2-8 lanes survive
        const float* xr = z_e + (size_t)n * DIM;
        const float* cr = cb + (size_t)myidx * DIM;
        float acc = 0.0f;
#pragma unroll 8
        for (int d = 0; d < DIM; d++)
            acc = __builtin_fmaf(xr[d], cr[d], acc);
        float dist = __builtin_fmaf(-2.0f, acc, xnorm[n]) + cnorm[myidx];
        key = ((u64)__float_as_uint(dist) << 32) | (unsigned)myidx;
    }
#pragma unroll
    for (int off = 1; off < 64; off <<= 1)
        key = u64min(key, __shfl_xor(key, off, 64));

    int idx = (int)(unsigned)(key & 0xffffffffu);
    if (key == ~0ULL) idx = 0;  // unreachable safety

    float4 x = *(const float4*)(z_e + (size_t)n * DIM + lane * 4);
    float4 c = *(const float4*)(cb + (size_t)idx * DIM + lane * 4);
    float4 st;
    st.x = x.x + (c.x - x.x); st.y = x.y + (c.y - x.y);
    st.z = x.z + (c.z - x.z); st.w = x.w + (c.w - x.w);
    *(float4*)(out_zq + (size_t)n * DIM + lane * 4) = st;

    float d0 = x.x - c.x, d1 = x.y - c.y, d2 = x.z - c.z, d3 = x.w - c.w;
    float s2 = (d0 * d0 + d1 * d1) + (d2 * d2 + d3 * d3);
#pragma unroll
    for (int off = 1; off < 64; off <<= 1)
        s2 += __shfl_xor(s2, off, 64);
    if (lane == 0) {
        rowloss[n] = s2;
        out_idx[n] = (float)idx;
    }
}

// ---------------------------------------------------------------- kernel D
__global__ __launch_bounds__(256) void vq_loss(const float* __restrict__ rowloss,
                                               float* __restrict__ out_loss) {
    __shared__ double sd[256];
    double s = 0.0;
    for (int i = threadIdx.x; i < N_ROWS; i += 256) s += (double)rowloss[i];
    sd[threadIdx.x] = s;
    __syncthreads();
    for (int off = 128; off; off >>= 1) {
        if (threadIdx.x < off) sd[threadIdx.x] += sd[threadIdx.x + off];
        __syncthreads();
    }
    if (threadIdx.x == 0) {
        double mean = sd[0] / (double)((size_t)N_ROWS * DIM);
        out_loss[0] = (float)(1.25 * mean);
    }
}

// ---------------------------------------------------------------- launch
extern "C" void kernel_launch(void* const* d_in, const int* in_sizes, int n_in,
                              void* d_out, int out_size, void* d_ws, size_t ws_size,
                              hipStream_t stream) {
    const float* z_e = (const float*)d_in[0];
    const float* cb  = (const float*)d_in[1];

    float* out   = (float*)d_out;
    float* zq    = out;
    float* oidx  = out + (size_t)N_ROWS * DIM;
    float* oloss = oidx + N_ROWS;

    // ws layout (~12.6 MB):
    //   zb   bf16[8192*256]  4 MB
    //   cbb  bf16[8192*256]  4 MB
    //   xnorm/cnorm/rowloss  3*32 KB
    //   cand_cnt int[SPLITK*N_ROWS]           512 KB  ([split][n] layout)
    //   cand_pk  u32[SPLITK*N_ROWS*GSLOTS]    4 MB    (bf16(dot)<<16 | idx)
    u16*      zb       = (u16*)d_ws;
    u16*      cbb      = zb + (size_t)N_ROWS * DIM;
    float*    xnorm    = (float*)(cbb + (size_t)K_CODES * DIM);
    float*    cnorm    = xnorm + N_ROWS;
    float*    rowloss  = cnorm + K_CODES;
    int*      cand_cnt = (int*)(rowloss + N_ROWS);
    unsigned* cand_pk  = (unsigned*)(cand_cnt + N_ROWS * SPLITK);

    vq_prep    <<<(N_ROWS + K_CODES) / 4, 256, 0, stream>>>(z_e, cb, zb, cbb, xnorm, cnorm);
    // grid (split, mtile): linear%8 == split%8 -> splits s, s+8 pinned to one
    // XCD; their 2x128KB bf16 codebook slices stay L2-resident.
    vq_mfma    <<<dim3(SPLITK, N_ROWS / 128), 256, 0, stream>>>(zb, cbb, cand_cnt, cand_pk);
    vq_finalize<<<N_ROWS / 4, 256, 0, stream>>>(z_e, cb, xnorm, cnorm, cand_cnt, cand_pk,
                                                zq, oidx, rowloss);
    vq_loss    <<<1, 256, 0, stream>>>(rowloss, oloss);
}

// Round 15
// 174.715 us; speedup vs baseline: 1.3792x; 1.3792x over previous
//
#include <hip/hip_runtime.h>
#include <stdint.h>

#define N_ROWS  8192   // B*S = 4*2048
#define DIM     256
#define K_CODES 8192
#define SPLITK  8
#define KS      1024          // codes per split
#define NT      128           // codes per K-tile
#define LSLOTS  15            // per-row append slots in LDS (LDS = exactly 48 KiB,
                              // breaks the power-of-2 stride: conflicts 150K -> 16K, R13)
#define GSLOTS  8             // per-row-split survivor slots in ws (top-8 by dot)
// acc-space (dot) margin: covers dist-bucket/2 (1.5e-5) + 2*bf16 dot err max
// (~4.5e-5) + dropped cnorm/2 (1.9e-6). 1e-4 leaves ~1.6x slack.
#define MARGIN_ACC 1.0e-4f
// finalize margin: MARGIN_ACC + 2x bf16 quantization of stored dots
// (|dot| <= ~0.04 -> qerr <= 6.3e-5 per side). 2.5e-4 covers 2.26e-4 worst.
#define MARGIN_FIN 2.5e-4f

typedef unsigned long long u64;
typedef unsigned short u16;
typedef short s16x8 __attribute__((ext_vector_type(8)));   // 8 bf16 = 4 VGPR
typedef float f32x4 __attribute__((ext_vector_type(4)));

__device__ __forceinline__ u64 u64min(u64 a, u64 b) { return a < b ? a : b; }

// float -> bf16 bits, round-to-nearest-even (no NaN inputs here)
__device__ __forceinline__ u16 f2bf(float f) {
    unsigned u = __float_as_uint(f);
    u += 0x7fffu + ((u >> 16) & 1u);
    return (u16)(u >> 16);
}

// async 16B global->LDS (dest = wave-uniform base + lane*16, HW-added)
__device__ __forceinline__ void gld16(void* lds, const void* g) {
    __builtin_amdgcn_global_load_lds(
        (const __attribute__((address_space(1))) unsigned int*)g,
        (__attribute__((address_space(3))) unsigned int*)lds, 16, 0, 0);
}

// Raw s_barrier with compiler memory fences on BOTH sides (naked builtin
// does not order memory at the compiler level).
__device__ __forceinline__ void block_barrier() {
    asm volatile("" ::: "memory");
    __builtin_amdgcn_s_barrier();
    asm volatile("" ::: "memory");
}

// ---------------------------------------------------------------- kernel A
// Fused: bf16 conversion of z_e & cb + row norms. One wave per row.
__global__ __launch_bounds__(256) void vq_prep(const float* __restrict__ z_e,
                                               const float* __restrict__ cb,
                                               u16* __restrict__ zb,
                                               u16* __restrict__ cbb,
                                               float* __restrict__ xnorm,
                                               float* __restrict__ cnorm) {
    int wid  = (blockIdx.x * 256 + threadIdx.x) >> 6;
    int lane = threadIdx.x & 63;
    const float* src; u16* d16; float* dn;
    if (wid < N_ROWS) { src = z_e + (size_t)wid * DIM; d16 = zb + (size_t)wid * DIM; dn = xnorm + wid; }
    else              { int k = wid - N_ROWS;
                        src = cb  + (size_t)k   * DIM; d16 = cbb + (size_t)k * DIM; dn = cnorm + k; }
    float4 v = *(const float4*)(src + lane * 4);
    ushort4 h;
    h.x = f2bf(v.x); h.y = f2bf(v.y); h.z = f2bf(v.z); h.w = f2bf(v.w);
    *(ushort4*)(d16 + lane * 4) = h;
    float s = (v.x * v.x + v.y * v.y) + (v.z * v.z + v.w * v.w);
#pragma unroll
    for (int off = 1; off < 64; off <<= 1)
        s += __shfl_xor(s, off, 64);
    if (lane == 0) *dn = s;
}

// ---------------------------------------------------------------- kernel B
// bf16 MFMA dot GEMM + per-row running MAX of dot (argmin dist == argmax dot)
// + margin-append. Block: 128 rows x 1024 codes (one split), 4 waves, each a
// 32-row slab owning ALL 128 codes of each tile.
//
// R15 = R10's best-verified structure (63-65us) + two verified orthogonal
// deltas applied to it:
//  * LSLOTS 16->15: breaks the power-of-2 LDS stride of lcd/lci
//    (conflicts 150K -> 16K, measured R13) and makes LDS exactly 48 KiB:
//    Cs 32768 + lcd 7680 + lci 7680 + lcnt 512 + gmaxs 512 = 49152.
//  * Packed candidates (bf16(dot)<<16)|idx + top-GSLOTS-by-dot filter +
//    finalize global margin-prefilter (verified R13).
// Schedule per chunk-iter (32 iters: 8 K-tiles x 4 dim-chunks), verified R10:
//   barrier -> STAGE(it+1) [slot whose readers drained last phase]
//   -> 16x ds_read_b128 + 32 MFMA on slot it&1 [-> epilogue at kt end]
//   -> vmcnt(0) lgkmcnt(0) -> fenced barrier
// Race-freedom: writers only touch the slot whose readers drained
// (lgkmcnt(0)) before the previous barrier; all barriers compiler-fenced.
__global__ __launch_bounds__(256, 2) void vq_mfma(const u16* __restrict__ zb,
                                                  const u16* __restrict__ cbb,
                                                  int* __restrict__ cand_cnt,
                                                  unsigned* __restrict__ cand_pk) {
    __shared__ u16   Cs[2][128 * 64];   // 32 KB ring: 2 x (128 code-rows x 64 dims), swizzled
    __shared__ float lcd[128 * LSLOTS];
    __shared__ int   lci[128 * LSLOTS];
    __shared__ int   lcnt[128];
    __shared__ float gmaxs[128];

    const int tid   = threadIdx.x;
    const int lane  = tid & 63;
    const int wave  = tid >> 6;
    const int quad  = lane >> 4;
    const int l16   = lane & 15;
    const int split = blockIdx.x;
    const int n0    = blockIdx.y * 128;

    if (tid < 128) lcnt[tid] = 0;

    // staging lane constants: lane covers (row srow8 of 8-group, dest chunk schunk)
    const int srow8  = lane >> 3;
    const int schunk = lane & 7;
    const int ssw    = (schunk ^ srow8) * 8;   // swizzled source chunk offset (shorts)
    const u16* csrc  = cbb + (size_t)split * KS * DIM + (size_t)srow8 * DIM + ssw;

    // ---- A fragments in registers (issued FIRST: retire under the first
    // vmcnt(0)). af[i][s]: row n0+wave*32+i*16+l16, dims s*32 + quad*8 .. +7
    s16x8 af[2][8];
#pragma unroll
    for (int i = 0; i < 2; i++) {
        const u16* p = zb + (size_t)(n0 + wave * 32 + i * 16 + l16) * DIM + quad * 8;
#pragma unroll
        for (int s = 0; s < 8; s++)
            af[i][s] = *(const s16x8*)(p + s * 32);
    }

    // stage chunk-iter s (code-tile s>>2, 64-dim chunk s&3) into Cs[slot]
    auto STAGE = [&](int s, int slot) {
        const u16* src = csrc + (size_t)(s >> 2) * (NT * DIM) + (s & 3) * 64;
#pragma unroll
        for (int t = 0; t < 4; t++) {
            int rg = wave * 4 + t;            // 8-code-row group, wave-uniform
            gld16(&Cs[slot][rg * 512], src + (size_t)rg * (8 * DIM));
        }
    };

    float runmax[8];
#pragma unroll
    for (int t = 0; t < 8; t++) runmax[t] = -3.0e38f;

    // prologue: stage(0) into slot 0; drain af(16)+stage0(16); publish.
    STAGE(0, 0);
    asm volatile("s_waitcnt vmcnt(0) lgkmcnt(0)" ::: "memory");
    block_barrier();

    for (int kt = 0; kt < KS / NT; kt++) {   // 8 K-tiles of 128 codes
        const int kbase = split * KS + kt * NT;
        f32x4 acc[2][8];
#pragma unroll
        for (int i = 0; i < 2; i++)
#pragma unroll
            for (int j = 0; j < 8; j++)
#pragma unroll
                for (int e = 0; e < 4; e++) acc[i][j][e] = 0.0f;

#pragma unroll
        for (int kc = 0; kc < 4; kc++) {     // 64-dim chunks, flat iter index
            const int it = (kt << 2) | kc;
            // issue next-chunk stage FIRST: it writes slot (it+1)&1, whose
            // readers (phase it-1) drained before the last barrier.
            if (it < 31) STAGE(it + 1, (it + 1) & 1);

            const u16* cbuf = &Cs[it & 1][0];    // staged(it); ready per barrier(it-1)
#pragma unroll
            for (int ks = 0; ks < 2; ks++) {
                s16x8 bfr[8];
#pragma unroll
                for (int j = 0; j < 8; j++)
                    bfr[j] = *(const s16x8*)&cbuf[(j * 16 + l16) * 64 +
                                                  (((ks << 2) | quad) ^ (l16 & 7)) * 8];
#pragma unroll
                for (int i = 0; i < 2; i++)
#pragma unroll
                    for (int j = 0; j < 8; j++)
                        acc[i][j] = __builtin_amdgcn_mfma_f32_16x16x32_bf16(
                            af[i][kc * 2 + ks], bfr[j], acc[i][j], 0, 0, 0);
            }

            // drain stage(it+1) (had a full compute phase of cover) + this
            // wave's LDS reads; fenced barrier publishes slot (it+1)&1.
            if (it < 31) {
                asm volatile("s_waitcnt vmcnt(0) lgkmcnt(0)" ::: "memory");
                block_barrier();
            }                                    // it==31: nothing outstanding
        }

        // ---- epilogue: in-wave row max over 8 code-frags, runmax update,
        // margin appends. Row rl = wave*32 + i*16 + quad*4 + r (wave-owned;
        // lcd/lci/lcnt never restaged -> no cross-phase race).
#pragma unroll
        for (int i = 0; i < 2; i++)
#pragma unroll
            for (int r = 0; r < 4; r++) {
                float m = fmaxf(fmaxf(fmaxf(acc[i][0][r], acc[i][1][r]),
                                      fmaxf(acc[i][2][r], acc[i][3][r])),
                                fmaxf(fmaxf(acc[i][4][r], acc[i][5][r]),
                                      fmaxf(acc[i][6][r], acc[i][7][r])));
                m = fmaxf(m, __shfl_xor(m, 1, 64));
                m = fmaxf(m, __shfl_xor(m, 2, 64));
                m = fmaxf(m, __shfl_xor(m, 4, 64));
                m = fmaxf(m, __shfl_xor(m, 8, 64));
                runmax[i * 4 + r] = fmaxf(runmax[i * 4 + r], m);
                float thr = runmax[i * 4 + r] - MARGIN_ACC;
                int rl = wave * 32 + i * 16 + quad * 4 + r;
#pragma unroll
                for (int j = 0; j < 8; j++) {
                    float d = acc[i][j][r];
                    if (d >= thr) {
                        int pos = atomicAdd(&lcnt[rl], 1);
                        if (pos < LSLOTS) {
                            lcd[rl * LSLOTS + pos] = d;
                            lci[rl * LSLOTS + pos] = kbase + j * 16 + l16;
                        }
                    }
                }
            }
    }

    if (l16 == 0) {
#pragma unroll
        for (int i = 0; i < 2; i++)
#pragma unroll
            for (int r = 0; r < 4; r++)
                gmaxs[wave * 32 + i * 16 + quad * 4 + r] = runmax[i * 4 + r];
    }
    __syncthreads();

    // filter appends vs final row max; keep TOP-GSLOTS BY DOT (replace-min,
    // fp32 selection); store packed (bf16(dot)<<16)|idx so finalize can
    // margin-prefilter globally. [split][n] layout: contiguous private range.
    if (tid < 128) {
        int n   = n0 + tid;
        int cnt = lcnt[tid]; if (cnt > LSLOTS) cnt = LSLOTS;
        float thrf = gmaxs[tid] - MARGIN_ACC;
        float bd[GSLOTS]; int bi[GSLOTS];
        int w = 0;
        for (int s = 0; s < cnt; s++) {
            float d = lcd[tid * LSLOTS + s];
            if (d < thrf) continue;
            if (w < GSLOTS) { bd[w] = d; bi[w] = lci[tid * LSLOTS + s]; w++; }
            else {
                int mn = 0;
#pragma unroll
                for (int k = 1; k < GSLOTS; k++) if (bd[k] < bd[mn]) mn = k;
                if (d > bd[mn]) { bd[mn] = d; bi[mn] = lci[tid * LSLOTS + s]; }
            }
        }
        int base = (split * N_ROWS + n) * GSLOTS;
        for (int k = 0; k < w; k++)
            cand_pk[base + k] = ((unsigned)f2bf(bd[k]) << 16) | (unsigned)bi[k];
        cand_cnt[split * N_ROWS + n] = w;
    }
}

// ---------------------------------------------------------------- kernel C
// Gather packed candidates; global margin prefilter on bf16 dots
// (dot >= max_dot - MARGIN_FIN retains the true winner incl. quantization);
// exact fp32 recheck of the ~2-8 survivors with numerics BIT-IDENTICAL to
// the passing version (sequential fmaf d=0..255, fmaf(-2,m,xn)+cn,
// lexicographic (dist,idx) min); gather + z_q_st + rowloss. One wave/row.
__global__ __launch_bounds__(256) void vq_finalize(const float* __restrict__ z_e,
                                                   const float* __restrict__ cb,
                                                   const float* __restrict__ xnorm,
                                                   const float* __restrict__ cnorm,
                                                   const int* __restrict__ cand_cnt,
                                                   const unsigned* __restrict__ cand_pk,
                                                   float* __restrict__ out_zq,
                                                   float* __restrict__ out_idx,
                                                   float* __restrict__ rowloss) {
    const int n    = blockIdx.x * 4 + (threadIdx.x >> 6);
    const int lane = threadIdx.x & 63;

    int   myidx = -1;
    float mydot = -3.0e38f;
    int t = 0;
#pragma unroll
    for (int s = 0; s < SPLITK; s++) {
        int c = cand_cnt[s * N_ROWS + n];
        if (lane >= t && lane < t + c) {
            unsigned key = cand_pk[(s * N_ROWS + n) * GSLOTS + (lane - t)];
            myidx = (int)(key & 0x1FFFu);
            mydot = __uint_as_float(key & 0xFFFF0000u);
        }
        t += c;
    }

    // global (row-wide) max of stored bf16 dots
    float mg = mydot;
#pragma unroll
    for (int off = 1; off < 64; off <<= 1)
        mg = fmaxf(mg, __shfl_xor(mg, off, 64));

    u64 key = ~0ULL;
    if (myidx >= 0 && mydot >= mg - MARGIN_FIN) {   // ~2-8 lanes survive
        const float* xr = z_e + (size_t)n * DIM;
        const float* cr = cb + (size_t)myidx * DIM;
        float acc = 0.0f;
#pragma unroll 8
        for (int d = 0; d < DIM; d++)
            acc = __builtin_fmaf(xr[d], cr[d], acc);
        float dist = __builtin_fmaf(-2.0f, acc, xnorm[n]) + cnorm[myidx];
        key = ((u64)__float_as_uint(dist) << 32) | (unsigned)myidx;
    }
#pragma unroll
    for (int off = 1; off < 64; off <<= 1)
        key = u64min(key, __shfl_xor(key, off, 64));

    int idx = (int)(unsigned)(key & 0xffffffffu);
    if (key == ~0ULL) idx = 0;  // unreachable safety

    float4 x = *(const float4*)(z_e + (size_t)n * DIM + lane * 4);
    float4 c = *(const float4*)(cb + (size_t)idx * DIM + lane * 4);
    float4 st;
    st.x = x.x + (c.x - x.x); st.y = x.y + (c.y - x.y);
    st.z = x.z + (c.z - x.z); st.w = x.w + (c.w - x.w);
    *(float4*)(out_zq + (size_t)n * DIM + lane * 4) = st;

    float d0 = x.x - c.x, d1 = x.y - c.y, d2 = x.z - c.z, d3 = x.w - c.w;
    float s2 = (d0 * d0 + d1 * d1) + (d2 * d2 + d3 * d3);
#pragma unroll
    for (int off = 1; off < 64; off <<= 1)
        s2 += __shfl_xor(s2, off, 64);
    if (lane == 0) {
        rowloss[n] = s2;
        out_idx[n] = (float)idx;
    }
}

// ---------------------------------------------------------------- kernel D
__global__ __launch_bounds__(256) void vq_loss(const float* __restrict__ rowloss,
                                               float* __restrict__ out_loss) {
    __shared__ double sd[256];
    double s = 0.0;
    for (int i = threadIdx.x; i < N_ROWS; i += 256) s += (double)rowloss[i];
    sd[threadIdx.x] = s;
    __syncthreads();
    for (int off = 128; off; off >>= 1) {
        if (threadIdx.x < off) sd[threadIdx.x] += sd[threadIdx.x + off];
        __syncthreads();
    }
    if (threadIdx.x == 0) {
        double mean = sd[0] / (double)((size_t)N_ROWS * DIM);
        out_loss[0] = (float)(1.25 * mean);
    }
}

// ---------------------------------------------------------------- launch
extern "C" void kernel_launch(void* const* d_in, const int* in_sizes, int n_in,
                              void* d_out, int out_size, void* d_ws, size_t ws_size,
                              hipStream_t stream) {
    const float* z_e = (const float*)d_in[0];
    const float* cb  = (const float*)d_in[1];

    float* out   = (float*)d_out;
    float* zq    = out;
    float* oidx  = out + (size_t)N_ROWS * DIM;
    float* oloss = oidx + N_ROWS;

    // ws layout (~10.5 MB):
    //   zb   bf16[8192*256]  4 MB
    //   cbb  bf16[8192*256]  4 MB
    //   xnorm/cnorm/rowloss  3*32 KB
    //   cand_cnt int[SPLITK*N_ROWS]           256 KB  ([split][n] layout)
    //   cand_pk  u32[SPLITK*N_ROWS*GSLOTS]    2 MB    (bf16(dot)<<16 | idx)
    u16*      zb       = (u16*)d_ws;
    u16*      cbb      = zb + (size_t)N_ROWS * DIM;
    float*    xnorm    = (float*)(cbb + (size_t)K_CODES * DIM);
    float*    cnorm    = xnorm + N_ROWS;
    float*    rowloss  = cnorm + K_CODES;
    int*      cand_cnt = (int*)(rowloss + N_ROWS);
    unsigned* cand_pk  = (unsigned*)(cand_cnt + N_ROWS * SPLITK);

    vq_prep    <<<(N_ROWS + K_CODES) / 4, 256, 0, stream>>>(z_e, cb, zb, cbb, xnorm, cnorm);
    // grid (split, mtile): linear%8 == split -> each split pinned to one XCD;
    // its 0.5MB bf16 codebook slice + zb rows stay L2-resident.
    vq_mfma    <<<dim3(SPLITK, N_ROWS / 128), 256, 0, stream>>>(zb, cbb, cand_cnt, cand_pk);
    vq_finalize<<<N_ROWS / 4, 256, 0, stream>>>(z_e, cb, xnorm, cnorm, cand_cnt, cand_pk,
                                                zq, oidx, rowloss);
    vq_loss    <<<1, 256, 0, stream>>>(rowloss, oloss);
}